// Round 1
// baseline (796.759 us; speedup 1.0000x reference)
//
#include <hip/hip_runtime.h>
#include <math.h>

#define CAP (1u<<20)

__device__ __forceinline__ unsigned f2key(float f){
  unsigned u = __float_as_uint(f);
  return (u & 0x80000000u) ? ~u : (u | 0x80000000u);
}
__device__ __forceinline__ float key2f(unsigned k){
  unsigned u = (k & 0x80000000u) ? (k & 0x7fffffffu) : ~k;
  return __uint_as_float(u);
}

// zero hists/counters, init min keys
__global__ void init_kernel(unsigned* ctrl){
  int tid = blockIdx.x*blockDim.x + threadIdx.x;
  int stride = gridDim.x*blockDim.x;
  for (int i=tid;i<12288;i+=stride) ctrl[i]=0u;
  if (tid<3){ ctrl[12288+tid]=0xFFFFFFFFu; ctrl[12291+tid]=0u; }
}

// 4096-bin histogram over key>>20, plus global min key
__global__ __launch_bounds__(256) void hist_kernel(const float4* __restrict__ data, int n4,
                            unsigned* __restrict__ hist, unsigned* __restrict__ minKey){
  __shared__ unsigned sh[4096];
  __shared__ unsigned sMin;
  int tid = threadIdx.x;
  for (int i=tid;i<4096;i+=blockDim.x) sh[i]=0u;
  if (tid==0) sMin=0xFFFFFFFFu;
  __syncthreads();
  unsigned lmin=0xFFFFFFFFu;
  int idx = blockIdx.x*blockDim.x + tid;
  int stride = gridDim.x*blockDim.x;
  for (int i=idx;i<n4;i+=stride){
    float4 v = data[i];
    unsigned k0=f2key(v.x), k1=f2key(v.y), k2=f2key(v.z), k3=f2key(v.w);
    atomicAdd(&sh[k0>>20],1u); atomicAdd(&sh[k1>>20],1u);
    atomicAdd(&sh[k2>>20],1u); atomicAdd(&sh[k3>>20],1u);
    lmin = min(lmin, min(min(k0,k1),min(k2,k3)));
  }
  atomicMin(&sMin, lmin);
  __syncthreads();
  for (int i=tid;i<4096;i+=blockDim.x){ unsigned c=sh[i]; if(c) atomicAdd(&hist[i],c); }
  if (tid==0) atomicMin(minKey, sMin);
}

// find bins containing top-ranks k1 (=R-1) and k2 (=R); binInfo = {b_lo, b_hi, cntAbove(b_hi)}
__global__ void findbin_kernel(const unsigned* __restrict__ hist, unsigned k1, unsigned k2,
                               unsigned* __restrict__ binInfo){
  unsigned cum=0, above=0; int b_hi=-1, b_lo=-1;
  for (int b=4095;b>=0;--b){
    unsigned h = hist[b];
    if (b_hi<0 && cum + h >= k1){ b_hi=b; above=cum; }
    cum += h;
    if (b_lo<0 && cum >= k2){ b_lo=b; break; }
  }
  binInfo[0]=(unsigned)b_lo; binInfo[1]=(unsigned)b_hi; binInfo[2]=above;
}

// collect elements whose bin in [b_lo, b_hi]
__global__ __launch_bounds__(256) void collect_kernel(const float4* __restrict__ data, int n4,
                               const unsigned* __restrict__ binInfo,
                               float* __restrict__ cand, unsigned* __restrict__ cnt){
  unsigned blo = binInfo[0], bhi = binInfo[1];
  int idx = blockIdx.x*blockDim.x + threadIdx.x;
  int stride = gridDim.x*blockDim.x;
  for (int i=idx;i<n4;i+=stride){
    float4 v = data[i];
    float r[4] = {v.x,v.y,v.z,v.w};
    #pragma unroll
    for (int j=0;j<4;j++){
      unsigned b = f2key(r[j]) >> 20;
      if (b>=blo && b<=bhi){
        unsigned p = atomicAdd(cnt,1u);
        if (p < CAP) cand[p] = r[j];
      }
    }
  }
}

// exact k1-th and k2-th largest via 32-step binary search on keys; write {mn, mx}
__global__ __launch_bounds__(1024) void select_kernel(const float* __restrict__ cand, const unsigned* __restrict__ cnt,
                              const unsigned* __restrict__ binInfo, const unsigned* __restrict__ minKey,
                              unsigned k1, unsigned k2, double frac, float* __restrict__ stats){
  __shared__ unsigned sCnt;
  __shared__ unsigned sKey[2];
  unsigned m = *cnt; if (m > CAP) m = CAP;
  unsigned above = binInfo[2];
  unsigned ks0 = k1 - above, ks1 = k2 - above;
  for (int t=0;t<2;t++){
    unsigned k = (t==0) ? ks0 : ks1;
    unsigned lo=0u, hi=0xFFFFFFFFu;
    while (lo < hi){
      unsigned mid = lo + ((hi - lo) >> 1) + 1u;
      if (threadIdx.x==0) sCnt=0u;
      __syncthreads();
      unsigned c=0;
      for (unsigned i=threadIdx.x;i<m;i+=blockDim.x) if (f2key(cand[i]) >= mid) c++;
      if (c) atomicAdd(&sCnt,c);
      __syncthreads();
      unsigned tot = sCnt;
      __syncthreads();
      if (tot >= k) lo = mid; else hi = mid - 1u;
    }
    if (threadIdx.x==0) sKey[t]=lo;
  }
  __syncthreads();
  if (threadIdx.x==0){
    float vhi = key2f(sKey[0]);   // (R-1)-th largest = a[i0+1]
    float vlo = key2f(sKey[1]);   // R-th largest     = a[i0]
    double mx = (double)vlo + frac * ((double)vhi - (double)vlo);
    float mxf = (float)mx;
    float mnraw = key2f(*minKey);
    float mnf = (mnraw >= 0.0f) ? mnraw : -mxf;
    stats[0]=mnf; stats[1]=mxf;
  }
}

// fake-quant with optional lut shrinkage; STE value semantics; in/out may alias
__global__ __launch_bounds__(256) void quant_kernel(const float4* __restrict__ in, float4* __restrict__ outp, int n4,
                             const float* __restrict__ stats, float lutMin){
  float mn = stats[0], mx = stats[1];
  float diff = mx - mn;
  float denom = diff + 1e-8f;
  float lp = lutMin * mx;
  float ln = lutMin * fabsf(mn);
  int idx = blockIdx.x*blockDim.x + threadIdx.x;
  int stride = gridDim.x*blockDim.x;
  for (int i=idx;i<n4;i+=stride){
    float4 v = in[i];
    float r[4] = {v.x,v.y,v.z,v.w};
    #pragma unroll
    for (int j=0;j<4;j++){
      float x = r[j];
      float q = fminf(fmaxf(x, mn), mx);
      q = (q - mn) / denom * 255.0f;
      q = rintf(q);
      q = q / 255.0f * diff + mn;
      if (lutMin > 0.0f){
        float pos = fmaxf(q, 0.0f);
        float neg = q - pos;
        pos = (pos < lp) ? lp : pos;
        neg = (neg > -ln) ? -ln : neg;
        q = pos + neg;
      }
      r[j] = x + (q - x);
    }
    outp[i] = make_float4(r[0],r[1],r[2],r[3]);
  }
}

// batched f32 GEMM: A[b] 2048x64 row-major, B[b] 64x2048 row-major -> C[b] 2048x2048
// fused epilogue: histogram + min of C into ho/minKeyO
__global__ __launch_bounds__(256) void matmul_kernel(const float* __restrict__ A, const float* __restrict__ B,
                              float* __restrict__ C,
                              unsigned* __restrict__ histO, unsigned* __restrict__ minKeyO){
  __shared__ float As[64*132];   // [k][m], padded stride 132 to break bank conflicts
  __shared__ float Bs[64*128];   // [k][n]
  __shared__ unsigned sMin;
  const int b = blockIdx.z;
  A += (size_t)b*2048*64;
  B += (size_t)b*64*2048;
  C += (size_t)b*2048*2048;
  const int brow = blockIdx.y*128, bcol = blockIdx.x*128;
  const int tid = threadIdx.x;
  // load A tile 128x64, store transposed
  #pragma unroll
  for (int i=0;i<8;i++){
    int f = tid + i*256;
    int r = f >> 4;            // 16 float4 per row
    int k4 = (f & 15) << 2;
    float4 v = *(const float4*)&A[(size_t)(brow + r)*64 + k4];
    As[(k4+0)*132 + r] = v.x;
    As[(k4+1)*132 + r] = v.y;
    As[(k4+2)*132 + r] = v.z;
    As[(k4+3)*132 + r] = v.w;
  }
  // load B tile 64x128
  #pragma unroll
  for (int i=0;i<8;i++){
    int f = tid + i*256;
    int k = f >> 5;            // 32 float4 per row
    int c4 = (f & 31) << 2;
    float4 v = *(const float4*)&B[(size_t)k*2048 + bcol + c4];
    *(float4*)&Bs[k*128 + c4] = v;
  }
  if (tid==0) sMin=0xFFFFFFFFu;
  __syncthreads();
  const int ty = tid >> 4, tx = tid & 15;
  const int m0 = ty*8, n0 = tx*8;
  float acc[8][8];
  #pragma unroll
  for (int i=0;i<8;i++)
    #pragma unroll
    for (int j=0;j<8;j++) acc[i][j]=0.0f;
  #pragma unroll 8
  for (int k=0;k<64;k++){
    float4 a0 = *(const float4*)(As + k*132 + m0);
    float4 a1 = *(const float4*)(As + k*132 + m0 + 4);
    float4 b0 = *(const float4*)(Bs + k*128 + n0);
    float4 b1 = *(const float4*)(Bs + k*128 + n0 + 4);
    float am[8] = {a0.x,a0.y,a0.z,a0.w,a1.x,a1.y,a1.z,a1.w};
    float bn[8] = {b0.x,b0.y,b0.z,b0.w,b1.x,b1.y,b1.z,b1.w};
    #pragma unroll
    for (int i=0;i<8;i++)
      #pragma unroll
      for (int j=0;j<8;j++)
        acc[i][j] = fmaf(am[i], bn[j], acc[i][j]);
  }
  __syncthreads();
  // epilogue: store + fused histogram/min (reuse As as 4096-bin LDS hist)
  unsigned* sh = (unsigned*)As;
  for (int i=tid;i<4096;i+=256) sh[i]=0u;
  __syncthreads();
  unsigned lmin=0xFFFFFFFFu;
  #pragma unroll
  for (int i=0;i<8;i++){
    int r = brow + m0 + i;
    float4 o0 = make_float4(acc[i][0],acc[i][1],acc[i][2],acc[i][3]);
    float4 o1 = make_float4(acc[i][4],acc[i][5],acc[i][6],acc[i][7]);
    *(float4*)&C[(size_t)r*2048 + bcol + n0]     = o0;
    *(float4*)&C[(size_t)r*2048 + bcol + n0 + 4] = o1;
    #pragma unroll
    for (int j=0;j<8;j++){
      unsigned kk = f2key(acc[i][j]);
      atomicAdd(&sh[kk>>20], 1u);
      lmin = min(lmin, kk);
    }
  }
  atomicMin(&sMin, lmin);
  __syncthreads();
  for (int i=tid;i<4096;i+=256){ unsigned c=sh[i]; if(c) atomicAdd(&histO[i],c); }
  if (tid==0) atomicMin(minKeyO, sMin);
}

static void percentile_ranks(long long n, double pct, unsigned& k1, unsigned& k2, double& frac){
  double p = (double)(n - 1) * (pct / 100.0);   // matches numpy's virtual index
  double fi = floor(p);
  frac = p - fi;
  long long i0 = (long long)fi;
  k2 = (unsigned)(n - i0);   // rank (from top) of a[i0]
  k1 = k2 - 1u;              // rank of a[i0+1]
}

extern "C" void kernel_launch(void* const* d_in, const int* in_sizes, int n_in,
                              void* d_out, int out_size, void* d_ws, size_t ws_size,
                              hipStream_t stream) {
  const float* x = (const float*)d_in[0];
  const float* y = (const float*)d_in[1];
  float* out = (float*)d_out;
  char* ws = (char*)d_ws;

  const long long nX = (long long)in_sizes[0];       // 1048576
  const long long nY = (long long)in_sizes[1];       // 1048576
  const long long nO = (long long)out_size;          // 33554432
  const int nX4 = (int)(nX/4), nY4 = (int)(nY/4), nO4 = (int)(nO/4);

  float*    xq    = (float*)(ws);
  float*    yq    = (float*)(ws + (5ll<<20));
  float*    candx = (float*)(ws + (10ll<<20));
  float*    candy = (float*)(ws + (15ll<<20));
  float*    cando = (float*)(ws + (20ll<<20));
  unsigned* ctrl  = (unsigned*)(ws + (25ll<<20));
  unsigned *hx = ctrl, *hy = ctrl+4096, *ho = ctrl+8192;
  unsigned* minkey = ctrl + 12288;   // [3]: x,y,o
  unsigned* cnt    = ctrl + 12291;   // [3]
  unsigned* bix    = ctrl + 12294;   // [3]
  unsigned* biy    = ctrl + 12297;
  unsigned* bio    = ctrl + 12300;
  float* stx = (float*)(ctrl + 12304);  // {mn,mx}
  float* sty = stx + 2;
  float* sto = stx + 4;

  unsigned k1x,k2x,k1y,k2y,k1o,k2o; double fx,fy,fo;
  percentile_ranks(nX, 99.99,   k1x, k2x, fx);
  percentile_ranks(nY, 98.0,    k1y, k2y, fy);
  percentile_ranks(nO, 99.9999, k1o, k2o, fo);

  init_kernel<<<48,256,0,stream>>>(ctrl);

  // ---- x stats + quant ----
  hist_kernel<<<128,256,0,stream>>>((const float4*)x, nX4, hx, minkey+0);
  findbin_kernel<<<1,1,0,stream>>>(hx, k1x, k2x, bix);
  collect_kernel<<<128,256,0,stream>>>((const float4*)x, nX4, bix, candx, cnt+0);
  select_kernel<<<1,1024,0,stream>>>(candx, cnt+0, bix, minkey+0, k1x, k2x, fx, stx);
  quant_kernel<<<256,256,0,stream>>>((const float4*)x, (float4*)xq, nX4, stx, 0.0f);

  // ---- y stats + quant (lut 0.05) ----
  hist_kernel<<<128,256,0,stream>>>((const float4*)y, nY4, hy, minkey+1);
  findbin_kernel<<<1,1,0,stream>>>(hy, k1y, k2y, biy);
  collect_kernel<<<128,256,0,stream>>>((const float4*)y, nY4, biy, candy, cnt+1);
  select_kernel<<<1,1024,0,stream>>>(candy, cnt+1, biy, minkey+1, k1y, k2y, fy, sty);
  quant_kernel<<<256,256,0,stream>>>((const float4*)y, (float4*)yq, nY4, sty, 0.05f);

  // ---- matmul (raw f32 out to d_out) + fused out-histogram/min ----
  matmul_kernel<<<dim3(16,16,8),256,0,stream>>>(xq, yq, out, ho, minkey+2);

  // ---- out stats + in-place quant (deterministic rounding; |err| <= 1 level) ----
  findbin_kernel<<<1,1,0,stream>>>(ho, k1o, k2o, bio);
  collect_kernel<<<2048,256,0,stream>>>((const float4*)out, nO4, bio, cando, cnt+2);
  select_kernel<<<1,1024,0,stream>>>(cando, cnt+2, bio, minkey+2, k1o, k2o, fo, sto);
  quant_kernel<<<2048,256,0,stream>>>((const float4*)out, (float4*)out, nO4, sto, 0.0f);
}

// Round 2
// 425.404 us; speedup vs baseline: 1.8729x; 1.8729x over previous
//
#include <hip/hip_runtime.h>
#include <math.h>

#define CAP  (1u<<20)
#define LCAP 12288

__device__ __forceinline__ unsigned f2key(float f){
  unsigned u = __float_as_uint(f);
  return (u & 0x80000000u) ? ~u : (u | 0x80000000u);
}
__device__ __forceinline__ float key2f(unsigned k){
  unsigned u = (k & 0x80000000u) ? (k & 0x7fffffffu) : ~k;
  return __uint_as_float(u);
}

// zero hists/counters, init min keys
__global__ void init_kernel(unsigned* ctrl){
  int tid = blockIdx.x*blockDim.x + threadIdx.x;
  int stride = gridDim.x*blockDim.x;
  for (int i=tid;i<12288;i+=stride) ctrl[i]=0u;
  if (tid<3){ ctrl[12288+tid]=0xFFFFFFFFu; ctrl[12291+tid]=0u; }
}

// 4096-bin histogram over key>>20, plus global min key; blockIdx.y picks tensor
__global__ __launch_bounds__(256) void hist2_kernel(
    const float4* __restrict__ dA, const float4* __restrict__ dB, int n4A, int n4B,
    unsigned* __restrict__ hA, unsigned* __restrict__ hB,
    unsigned* __restrict__ mkA, unsigned* __restrict__ mkB){
  const int z = blockIdx.y;
  const float4* __restrict__ data = z ? dB : dA;
  const int n4 = z ? n4B : n4A;
  unsigned* hist = z ? hB : hA;
  unsigned* minKey = z ? mkB : mkA;
  __shared__ unsigned sh[4096];
  __shared__ unsigned sMin;
  int tid = threadIdx.x;
  for (int i=tid;i<4096;i+=blockDim.x) sh[i]=0u;
  if (tid==0) sMin=0xFFFFFFFFu;
  __syncthreads();
  unsigned lmin=0xFFFFFFFFu;
  int idx = blockIdx.x*blockDim.x + tid;
  int stride = gridDim.x*blockDim.x;
  for (int i=idx;i<n4;i+=stride){
    float4 v = data[i];
    unsigned k0=f2key(v.x), k1=f2key(v.y), k2=f2key(v.z), k3=f2key(v.w);
    atomicAdd(&sh[k0>>20],1u); atomicAdd(&sh[k1>>20],1u);
    atomicAdd(&sh[k2>>20],1u); atomicAdd(&sh[k3>>20],1u);
    lmin = min(lmin, min(min(k0,k1),min(k2,k3)));
  }
  atomicMin(&sMin, lmin);
  __syncthreads();
  for (int i=tid;i<4096;i+=blockDim.x){ unsigned c=sh[i]; if(c) atomicAdd(&hist[i],c); }
  if (tid==0) atomicMin(minKey, sMin);
}

// parallel findbin: blockIdx.x picks tensor. 256 thr, 16 bins/thread, suffix scan.
// binInfo = {b_lo, b_hi, cntAbove(b_hi)}
__global__ __launch_bounds__(256) void findbin2_kernel(
    const unsigned* __restrict__ histA, const unsigned* __restrict__ histB,
    unsigned k1A, unsigned k2A, unsigned k1B, unsigned k2B,
    unsigned* __restrict__ biA, unsigned* __restrict__ biB){
  const int z = blockIdx.x;
  const unsigned* __restrict__ hist = z ? histB : histA;
  const unsigned k1 = z ? k1B : k1A;
  const unsigned k2 = z ? k2B : k2A;
  unsigned* bi = z ? biB : biA;
  __shared__ unsigned part[256];
  const int t = threadIdx.x;
  unsigned h[16];
  unsigned s = 0;
  #pragma unroll
  for (int i=0;i<16;i++){ h[i] = hist[t*16+i]; s += h[i]; }
  part[t] = s;
  __syncthreads();
  // inclusive suffix scan (Hillis-Steele)
  for (int off=1; off<256; off<<=1){
    unsigned add = (t+off<256) ? part[t+off] : 0u;
    __syncthreads();
    part[t] += add;
    __syncthreads();
  }
  unsigned cum = (t<255) ? part[t+1] : 0u;   // exclusive: sum of bins above this chunk
  // walk own bins high -> low
  for (int i=15;i>=0;--i){
    unsigned hh = h[i];
    unsigned b = (unsigned)(t*16+i);
    if (cum < k1 && cum + hh >= k1){ bi[1] = b; bi[2] = cum; }
    if (cum < k2 && cum + hh >= k2){ bi[0] = b; }
    cum += hh;
  }
}

// collect elements whose bin in [b_lo, b_hi]; blockIdx.y picks tensor
__global__ __launch_bounds__(256) void collect2_kernel(
    const float4* __restrict__ dA, const float4* __restrict__ dB, int n4A, int n4B,
    const unsigned* __restrict__ biA, const unsigned* __restrict__ biB,
    float* __restrict__ candA, float* __restrict__ candB,
    unsigned* __restrict__ cntA, unsigned* __restrict__ cntB){
  const int z = blockIdx.y;
  const float4* __restrict__ data = z ? dB : dA;
  const int n4 = z ? n4B : n4A;
  const unsigned* bi = z ? biB : biA;
  float* cand = z ? candB : candA;
  unsigned* cnt = z ? cntB : cntA;
  unsigned blo = bi[0], bhi = bi[1];
  int idx = blockIdx.x*blockDim.x + threadIdx.x;
  int stride = gridDim.x*blockDim.x;
  for (int i=idx;i<n4;i+=stride){
    float4 v = data[i];
    float r[4] = {v.x,v.y,v.z,v.w};
    #pragma unroll
    for (int j=0;j<4;j++){
      unsigned b = f2key(r[j]) >> 20;
      if (b>=blo && b<=bhi){
        unsigned p = atomicAdd(cnt,1u);
        if (p < CAP) cand[p] = r[j];
      }
    }
  }
}

// exact top-k1/k2 via 4-pass radix select over LDS-cached candidates; write {mn, mx}
__global__ __launch_bounds__(1024) void select2_kernel(
    const float* __restrict__ candA, const float* __restrict__ candB,
    const unsigned* __restrict__ cntA, const unsigned* __restrict__ cntB,
    const unsigned* __restrict__ biA, const unsigned* __restrict__ biB,
    const unsigned* __restrict__ mkA, const unsigned* __restrict__ mkB,
    unsigned k1A, unsigned k2A, unsigned k1B, unsigned k2B,
    double fracA, double fracB,
    float* __restrict__ stA, float* __restrict__ stB){
  const int z = blockIdx.x;
  const float* __restrict__ cand = z ? candB : candA;
  const unsigned* cnt = z ? cntB : cntA;
  const unsigned* bi  = z ? biB  : biA;
  const unsigned* mk  = z ? mkB  : mkA;
  const unsigned k1 = z ? k1B : k1A;
  const unsigned k2 = z ? k2B : k2A;
  const double frac = z ? fracB : fracA;
  float* stats = z ? stB : stA;

  __shared__ unsigned keys[LCAP];
  __shared__ unsigned hist[256];
  __shared__ unsigned sPrefix, sK;
  __shared__ unsigned sKey[2];
  const int t = threadIdx.x;
  unsigned m = *cnt; if (m > CAP) m = CAP;
  unsigned above = bi[2];
  for (unsigned i=t; i<m && i<LCAP; i+=1024) keys[i] = f2key(cand[i]);
  __syncthreads();

  for (int tg=0; tg<2; ++tg){
    unsigned k = ((tg==0) ? k1 : k2) - above;  // rank (from top) within candidate set
    unsigned prefix = 0u, pmask = 0u;
    for (int s=24; s>=0; s-=8){
      if (t<256) hist[t]=0u;
      __syncthreads();
      for (unsigned i=t;i<m;i+=1024){
        unsigned key = (i<LCAP) ? keys[i] : f2key(cand[i]);
        if ((key & pmask) == prefix) atomicAdd(&hist[(key>>s)&255u],1u);
      }
      __syncthreads();
      if (t==0){
        unsigned cum=0; int bsel=0;
        for (int b=255;b>=0;--b){
          unsigned hh=hist[b];
          if (cum + hh >= k){ bsel=b; break; }
          cum += hh;
        }
        sPrefix = prefix | ((unsigned)bsel << s);
        sK = k - cum;
      }
      __syncthreads();
      prefix = sPrefix;
      pmask |= (255u << s);
      k = sK;
      __syncthreads();
    }
    if (t==0) sKey[tg] = prefix;
  }
  __syncthreads();
  if (t==0){
    float vhi = key2f(sKey[0]);   // (R-1)-th largest = a[i0+1]
    float vlo = key2f(sKey[1]);   // R-th largest     = a[i0]
    double mx = (double)vlo + frac * ((double)vhi - (double)vlo);
    float mxf = (float)mx;
    float mnraw = key2f(*mk);
    float mnf = (mnraw >= 0.0f) ? mnraw : -mxf;
    stats[0]=mnf; stats[1]=mxf;
  }
}

// fake-quant with optional lut shrinkage; STE value semantics; in/out may alias
// blockIdx.y picks tensor
__global__ __launch_bounds__(256) void quant2_kernel(
    const float4* __restrict__ inA, const float4* __restrict__ inB,
    float4* __restrict__ outA, float4* __restrict__ outB, int n4A, int n4B,
    const float* __restrict__ stA, const float* __restrict__ stB,
    float lutA, float lutB){
  const int z = blockIdx.y;
  const float4* __restrict__ in = z ? inB : inA;
  float4* outp = z ? outB : outA;
  const int n4 = z ? n4B : n4A;
  const float* stats = z ? stB : stA;
  const float lutMin = z ? lutB : lutA;
  float mn = stats[0], mx = stats[1];
  float diff = mx - mn;
  float denom = diff + 1e-8f;
  float lp = lutMin * mx;
  float ln = lutMin * fabsf(mn);
  int idx = blockIdx.x*blockDim.x + threadIdx.x;
  int stride = gridDim.x*blockDim.x;
  for (int i=idx;i<n4;i+=stride){
    float4 v = in[i];
    float r[4] = {v.x,v.y,v.z,v.w};
    #pragma unroll
    for (int j=0;j<4;j++){
      float x = r[j];
      float q = fminf(fmaxf(x, mn), mx);
      q = (q - mn) / denom * 255.0f;
      q = rintf(q);
      q = q / 255.0f * diff + mn;
      if (lutMin > 0.0f){
        float pos = fmaxf(q, 0.0f);
        float neg = q - pos;
        pos = (pos < lp) ? lp : pos;
        neg = (neg > -ln) ? -ln : neg;
        q = pos + neg;
      }
      r[j] = x + (q - x);
    }
    outp[i] = make_float4(r[0],r[1],r[2],r[3]);
  }
}

// batched f32 GEMM: A[b] 2048x64 row-major, B[b] 64x2048 row-major -> C[b] 2048x2048
// fused epilogue: histogram + min of C into histO/minKeyO
__global__ __launch_bounds__(256) void matmul_kernel(const float* __restrict__ A, const float* __restrict__ B,
                              float* __restrict__ C,
                              unsigned* __restrict__ histO, unsigned* __restrict__ minKeyO){
  __shared__ float As[64*132];   // [k][m], padded stride 132
  __shared__ float Bs[64*128];   // [k][n]
  __shared__ unsigned sMin;
  const int b = blockIdx.z;
  A += (size_t)b*2048*64;
  B += (size_t)b*64*2048;
  C += (size_t)b*2048*2048;
  const int brow = blockIdx.y*128, bcol = blockIdx.x*128;
  const int tid = threadIdx.x;
  #pragma unroll
  for (int i=0;i<8;i++){
    int f = tid + i*256;
    int r = f >> 4;
    int k4 = (f & 15) << 2;
    float4 v = *(const float4*)&A[(size_t)(brow + r)*64 + k4];
    As[(k4+0)*132 + r] = v.x;
    As[(k4+1)*132 + r] = v.y;
    As[(k4+2)*132 + r] = v.z;
    As[(k4+3)*132 + r] = v.w;
  }
  #pragma unroll
  for (int i=0;i<8;i++){
    int f = tid + i*256;
    int k = f >> 5;
    int c4 = (f & 31) << 2;
    float4 v = *(const float4*)&B[(size_t)k*2048 + bcol + c4];
    *(float4*)&Bs[k*128 + c4] = v;
  }
  if (tid==0) sMin=0xFFFFFFFFu;
  __syncthreads();
  const int ty = tid >> 4, tx = tid & 15;
  const int m0 = ty*8, n0 = tx*8;
  float acc[8][8];
  #pragma unroll
  for (int i=0;i<8;i++)
    #pragma unroll
    for (int j=0;j<8;j++) acc[i][j]=0.0f;
  #pragma unroll 8
  for (int k=0;k<64;k++){
    float4 a0 = *(const float4*)(As + k*132 + m0);
    float4 a1 = *(const float4*)(As + k*132 + m0 + 4);
    float4 b0 = *(const float4*)(Bs + k*128 + n0);
    float4 b1 = *(const float4*)(Bs + k*128 + n0 + 4);
    float am[8] = {a0.x,a0.y,a0.z,a0.w,a1.x,a1.y,a1.z,a1.w};
    float bn[8] = {b0.x,b0.y,b0.z,b0.w,b1.x,b1.y,b1.z,b1.w};
    #pragma unroll
    for (int i=0;i<8;i++)
      #pragma unroll
      for (int j=0;j<8;j++)
        acc[i][j] = fmaf(am[i], bn[j], acc[i][j]);
  }
  __syncthreads();
  unsigned* sh = (unsigned*)As;
  for (int i=tid;i<4096;i+=256) sh[i]=0u;
  __syncthreads();
  unsigned lmin=0xFFFFFFFFu;
  #pragma unroll
  for (int i=0;i<8;i++){
    int r = brow + m0 + i;
    float4 o0 = make_float4(acc[i][0],acc[i][1],acc[i][2],acc[i][3]);
    float4 o1 = make_float4(acc[i][4],acc[i][5],acc[i][6],acc[i][7]);
    *(float4*)&C[(size_t)r*2048 + bcol + n0]     = o0;
    *(float4*)&C[(size_t)r*2048 + bcol + n0 + 4] = o1;
    #pragma unroll
    for (int j=0;j<8;j++){
      unsigned kk = f2key(acc[i][j]);
      atomicAdd(&sh[kk>>20], 1u);
      lmin = min(lmin, kk);
    }
  }
  atomicMin(&sMin, lmin);
  __syncthreads();
  for (int i=tid;i<4096;i+=256){ unsigned c=sh[i]; if(c) atomicAdd(&histO[i],c); }
  if (tid==0) atomicMin(minKeyO, sMin);
}

static void percentile_ranks(long long n, double pct, unsigned& k1, unsigned& k2, double& frac){
  double p = (double)(n - 1) * (pct / 100.0);
  double fi = floor(p);
  frac = p - fi;
  long long i0 = (long long)fi;
  k2 = (unsigned)(n - i0);   // rank (from top) of a[i0]
  k1 = k2 - 1u;              // rank of a[i0+1]
}

extern "C" void kernel_launch(void* const* d_in, const int* in_sizes, int n_in,
                              void* d_out, int out_size, void* d_ws, size_t ws_size,
                              hipStream_t stream) {
  const float* x = (const float*)d_in[0];
  const float* y = (const float*)d_in[1];
  float* out = (float*)d_out;
  char* ws = (char*)d_ws;

  const long long nX = (long long)in_sizes[0];       // 1048576
  const long long nY = (long long)in_sizes[1];       // 1048576
  const long long nO = (long long)out_size;          // 33554432
  const int nX4 = (int)(nX/4), nY4 = (int)(nY/4), nO4 = (int)(nO/4);

  float*    xq    = (float*)(ws);
  float*    yq    = (float*)(ws + (5ll<<20));
  float*    candx = (float*)(ws + (10ll<<20));
  float*    candy = (float*)(ws + (15ll<<20));
  float*    cando = (float*)(ws + (20ll<<20));
  unsigned* ctrl  = (unsigned*)(ws + (25ll<<20));
  unsigned *hx = ctrl, *hy = ctrl+4096, *ho = ctrl+8192;
  unsigned* minkey = ctrl + 12288;   // [3]: x,y,o
  unsigned* cnt    = ctrl + 12291;   // [3]
  unsigned* bix    = ctrl + 12294;   // [3] each
  unsigned* biy    = ctrl + 12297;
  unsigned* bio    = ctrl + 12300;
  float* stx = (float*)(ctrl + 12304);  // {mn,mx}
  float* sty = stx + 2;
  float* sto = stx + 4;

  unsigned k1x,k2x,k1y,k2y,k1o,k2o; double fx,fy,fo;
  percentile_ranks(nX, 99.99,   k1x, k2x, fx);
  percentile_ranks(nY, 98.0,    k1y, k2y, fy);
  percentile_ranks(nO, 99.9999, k1o, k2o, fo);

  init_kernel<<<48,256,0,stream>>>(ctrl);

  // ---- x & y stats + quant (merged dual-tensor pipeline) ----
  hist2_kernel<<<dim3(128,2),256,0,stream>>>((const float4*)x,(const float4*)y,nX4,nY4,hx,hy,minkey+0,minkey+1);
  findbin2_kernel<<<2,256,0,stream>>>(hx,hy,k1x,k2x,k1y,k2y,bix,biy);
  collect2_kernel<<<dim3(128,2),256,0,stream>>>((const float4*)x,(const float4*)y,nX4,nY4,bix,biy,candx,candy,cnt+0,cnt+1);
  select2_kernel<<<2,1024,0,stream>>>(candx,candy,cnt+0,cnt+1,bix,biy,minkey+0,minkey+1,
                                      k1x,k2x,k1y,k2y,fx,fy,stx,sty);
  quant2_kernel<<<dim3(256,2),256,0,stream>>>((const float4*)x,(const float4*)y,(float4*)xq,(float4*)yq,
                                              nX4,nY4,stx,sty,0.0f,0.05f);

  // ---- matmul (raw f32 out to d_out) + fused out-histogram/min ----
  matmul_kernel<<<dim3(16,16,8),256,0,stream>>>(xq, yq, out, ho, minkey+2);

  // ---- out stats + in-place quant (deterministic rounding; |err| <= 1 level) ----
  findbin2_kernel<<<1,256,0,stream>>>(ho,ho,k1o,k2o,k1o,k2o,bio,bio);
  collect2_kernel<<<dim3(2048,1),256,0,stream>>>((const float4*)out,(const float4*)out,nO4,nO4,bio,bio,cando,cando,cnt+2,cnt+2);
  select2_kernel<<<1,1024,0,stream>>>(cando,cando,cnt+2,cnt+2,bio,bio,minkey+2,minkey+2,
                                      k1o,k2o,k1o,k2o,fo,fo,sto,sto);
  quant2_kernel<<<dim3(2048,1),256,0,stream>>>((const float4*)out,(const float4*)out,(float4*)out,(float4*)out,
                                               nO4,nO4,sto,sto,0.0f,0.0f);
}

// Round 3
// 326.254 us; speedup vs baseline: 2.4421x; 1.3039x over previous
//
#include <hip/hip_runtime.h>
#include <math.h>

#define CAP  (1u<<20)
#define LCAP 12288

__device__ __forceinline__ unsigned f2key(float f){
  unsigned u = __float_as_uint(f);
  return (u & 0x80000000u) ? ~u : (u | 0x80000000u);
}
__device__ __forceinline__ float key2f(unsigned k){
  unsigned u = (k & 0x80000000u) ? (k & 0x7fffffffu) : ~k;
  return __uint_as_float(u);
}

// zero hists/counters, init min keys
__global__ void init_kernel(unsigned* ctrl){
  int tid = blockIdx.x*blockDim.x + threadIdx.x;
  int stride = gridDim.x*blockDim.x;
  for (int i=tid;i<12288;i+=stride) ctrl[i]=0u;
  if (tid<3){ ctrl[12288+tid]=0xFFFFFFFFu; ctrl[12291+tid]=0u; }
}

// 4096-bin histogram over key>>20, plus global min key; blockIdx.y picks tensor
__global__ __launch_bounds__(256) void hist2_kernel(
    const float4* __restrict__ dA, const float4* __restrict__ dB, int n4A, int n4B,
    unsigned* __restrict__ hA, unsigned* __restrict__ hB,
    unsigned* __restrict__ mkA, unsigned* __restrict__ mkB){
  const int z = blockIdx.y;
  const float4* __restrict__ data = z ? dB : dA;
  const int n4 = z ? n4B : n4A;
  unsigned* hist = z ? hB : hA;
  unsigned* minKey = z ? mkB : mkA;
  __shared__ unsigned sh[4096];
  __shared__ unsigned sMin;
  int tid = threadIdx.x;
  for (int i=tid;i<4096;i+=blockDim.x) sh[i]=0u;
  if (tid==0) sMin=0xFFFFFFFFu;
  __syncthreads();
  unsigned lmin=0xFFFFFFFFu;
  int idx = blockIdx.x*blockDim.x + tid;
  int stride = gridDim.x*blockDim.x;
  for (int i=idx;i<n4;i+=stride){
    float4 v = data[i];
    unsigned k0=f2key(v.x), k1=f2key(v.y), k2=f2key(v.z), k3=f2key(v.w);
    atomicAdd(&sh[k0>>20],1u); atomicAdd(&sh[k1>>20],1u);
    atomicAdd(&sh[k2>>20],1u); atomicAdd(&sh[k3>>20],1u);
    lmin = min(lmin, min(min(k0,k1),min(k2,k3)));
  }
  atomicMin(&sMin, lmin);
  __syncthreads();
  for (int i=tid;i<4096;i+=blockDim.x){ unsigned c=sh[i]; if(c) atomicAdd(&hist[i],c); }
  if (tid==0) atomicMin(minKey, sMin);
}

// parallel findbin: blockIdx.x picks tensor. 256 thr, 16 bins/thread, suffix scan.
// binInfo = {b_lo, b_hi, cntAbove(b_hi)}
__global__ __launch_bounds__(256) void findbin2_kernel(
    const unsigned* __restrict__ histA, const unsigned* __restrict__ histB,
    unsigned k1A, unsigned k2A, unsigned k1B, unsigned k2B,
    unsigned* __restrict__ biA, unsigned* __restrict__ biB){
  const int z = blockIdx.x;
  const unsigned* __restrict__ hist = z ? histB : histA;
  const unsigned k1 = z ? k1B : k1A;
  const unsigned k2 = z ? k2B : k2A;
  unsigned* bi = z ? biB : biA;
  __shared__ unsigned part[256];
  const int t = threadIdx.x;
  unsigned h[16];
  unsigned s = 0;
  #pragma unroll
  for (int i=0;i<16;i++){ h[i] = hist[t*16+i]; s += h[i]; }
  part[t] = s;
  __syncthreads();
  for (int off=1; off<256; off<<=1){
    unsigned add = (t+off<256) ? part[t+off] : 0u;
    __syncthreads();
    part[t] += add;
    __syncthreads();
  }
  unsigned cum = (t<255) ? part[t+1] : 0u;   // sum of bins above this chunk
  for (int i=15;i>=0;--i){
    unsigned hh = h[i];
    unsigned b = (unsigned)(t*16+i);
    if (cum < k1 && cum + hh >= k1){ bi[1] = b; bi[2] = cum; }
    if (cum < k2 && cum + hh >= k2){ bi[0] = b; }
    cum += hh;
  }
}

// collect elements whose bin in [b_lo, b_hi]; blockIdx.y picks tensor
__global__ __launch_bounds__(256) void collect2_kernel(
    const float4* __restrict__ dA, const float4* __restrict__ dB, int n4A, int n4B,
    const unsigned* __restrict__ biA, const unsigned* __restrict__ biB,
    float* __restrict__ candA, float* __restrict__ candB,
    unsigned* __restrict__ cntA, unsigned* __restrict__ cntB){
  const int z = blockIdx.y;
  const float4* __restrict__ data = z ? dB : dA;
  const int n4 = z ? n4B : n4A;
  const unsigned* bi = z ? biB : biA;
  float* cand = z ? candB : candA;
  unsigned* cnt = z ? cntB : cntA;
  unsigned blo = bi[0], bhi = bi[1];
  int idx = blockIdx.x*blockDim.x + threadIdx.x;
  int stride = gridDim.x*blockDim.x;
  for (int i=idx;i<n4;i+=stride){
    float4 v = data[i];
    float r[4] = {v.x,v.y,v.z,v.w};
    #pragma unroll
    for (int j=0;j<4;j++){
      unsigned b = f2key(r[j]) >> 20;
      if (b>=blo && b<=bhi){
        unsigned p = atomicAdd(cnt,1u);
        if (p < CAP) cand[p] = r[j];
      }
    }
  }
}

// exact top-k1/k2 via 4-pass radix select over LDS-cached candidates; write {mn, mx}
// bin-selection scan is a parallel 256-entry suffix scan (was the 97us serial hot spot)
__global__ __launch_bounds__(1024) void select2_kernel(
    const float* __restrict__ candA, const float* __restrict__ candB,
    const unsigned* __restrict__ cntA, const unsigned* __restrict__ cntB,
    const unsigned* __restrict__ biA, const unsigned* __restrict__ biB,
    const unsigned* __restrict__ mkA, const unsigned* __restrict__ mkB,
    unsigned k1A, unsigned k2A, unsigned k1B, unsigned k2B,
    double fracA, double fracB,
    float* __restrict__ stA, float* __restrict__ stB){
  const int z = blockIdx.x;
  const float* __restrict__ cand = z ? candB : candA;
  const unsigned* cnt = z ? cntB : cntA;
  const unsigned* bi  = z ? biB  : biA;
  const unsigned* mk  = z ? mkB  : mkA;
  const unsigned k1 = z ? k1B : k1A;
  const unsigned k2 = z ? k2B : k2A;
  const double frac = z ? fracB : fracA;
  float* stats = z ? stB : stA;

  __shared__ unsigned keys[LCAP];
  __shared__ unsigned hist[256];
  __shared__ unsigned scan[256];
  __shared__ unsigned sPrefix, sK;
  __shared__ unsigned sKey[2];
  const int t = threadIdx.x;
  unsigned m = *cnt; if (m > CAP) m = CAP;
  unsigned above = bi[2];
  for (unsigned i=t; i<m && i<LCAP; i+=1024) keys[i] = f2key(cand[i]);
  __syncthreads();

  for (int tg=0; tg<2; ++tg){
    unsigned k = ((tg==0) ? k1 : k2) - above;  // rank (from top) within candidate set
    unsigned prefix = 0u, pmask = 0u;
    for (int s=24; s>=0; s-=8){
      if (t<256) hist[t]=0u;
      __syncthreads();
      for (unsigned i=t;i<m;i+=1024){
        unsigned key = (i<LCAP) ? keys[i] : f2key(cand[i]);
        if ((key & pmask) == prefix) atomicAdd(&hist[(key>>s)&255u],1u);
      }
      __syncthreads();
      // parallel suffix scan over 256 bins
      if (t<256) scan[t] = hist[t];
      __syncthreads();
      for (int off=1; off<256; off<<=1){
        unsigned add = (t<256 && t+off<256) ? scan[t+off] : 0u;
        __syncthreads();
        if (t<256) scan[t] += add;
        __syncthreads();
      }
      if (t<256){
        unsigned cumAbove = (t<255) ? scan[t+1] : 0u;  // strictly-above count
        if (cumAbove < k && cumAbove + hist[t] >= k){  // unique t satisfies this
          sPrefix = prefix | ((unsigned)t << s);
          sK = k - cumAbove;
        }
      }
      __syncthreads();
      prefix = sPrefix;
      pmask |= (255u << s);
      k = sK;
      __syncthreads();
    }
    if (t==0) sKey[tg] = prefix;
  }
  __syncthreads();
  if (t==0){
    float vhi = key2f(sKey[0]);   // (R-1)-th largest = a[i0+1]
    float vlo = key2f(sKey[1]);   // R-th largest     = a[i0]
    double mx = (double)vlo + frac * ((double)vhi - (double)vlo);
    float mxf = (float)mx;
    float mnraw = key2f(*mk);
    float mnf = (mnraw >= 0.0f) ? mnraw : -mxf;
    stats[0]=mnf; stats[1]=mxf;
  }
}

// fake-quant with optional lut shrinkage; STE value semantics; in/out may alias
// blockIdx.y picks tensor
__global__ __launch_bounds__(256) void quant2_kernel(
    const float4* __restrict__ inA, const float4* __restrict__ inB,
    float4* __restrict__ outA, float4* __restrict__ outB, int n4A, int n4B,
    const float* __restrict__ stA, const float* __restrict__ stB,
    float lutA, float lutB){
  const int z = blockIdx.y;
  const float4* __restrict__ in = z ? inB : inA;
  float4* outp = z ? outB : outA;
  const int n4 = z ? n4B : n4A;
  const float* stats = z ? stB : stA;
  const float lutMin = z ? lutB : lutA;
  float mn = stats[0], mx = stats[1];
  float diff = mx - mn;
  float denom = diff + 1e-8f;
  float lp = lutMin * mx;
  float ln = lutMin * fabsf(mn);
  int idx = blockIdx.x*blockDim.x + threadIdx.x;
  int stride = gridDim.x*blockDim.x;
  for (int i=idx;i<n4;i+=stride){
    float4 v = in[i];
    float r[4] = {v.x,v.y,v.z,v.w};
    #pragma unroll
    for (int j=0;j<4;j++){
      float x = r[j];
      float q = fminf(fmaxf(x, mn), mx);
      q = (q - mn) / denom * 255.0f;
      q = rintf(q);
      q = q / 255.0f * diff + mn;
      if (lutMin > 0.0f){
        float pos = fmaxf(q, 0.0f);
        float neg = q - pos;
        pos = (pos < lp) ? lp : pos;
        neg = (neg > -ln) ? -ln : neg;
        q = pos + neg;
      }
      r[j] = x + (q - x);
    }
    outp[i] = make_float4(r[0],r[1],r[2],r[3]);
  }
}

// batched f32 GEMM: A[b] 2048x64 row-major, B[b] 64x2048 row-major -> C[b] 2048x2048
// fused epilogue: histogram + min of C into histO/minKeyO
__global__ __launch_bounds__(256) void matmul_kernel(const float* __restrict__ A, const float* __restrict__ B,
                              float* __restrict__ C,
                              unsigned* __restrict__ histO, unsigned* __restrict__ minKeyO){
  __shared__ float As[64*132];   // [k][m], padded stride 132
  __shared__ float Bs[64*128];   // [k][n]
  __shared__ unsigned sMin;
  const int b = blockIdx.z;
  A += (size_t)b*2048*64;
  B += (size_t)b*64*2048;
  C += (size_t)b*2048*2048;
  const int brow = blockIdx.y*128, bcol = blockIdx.x*128;
  const int tid = threadIdx.x;
  #pragma unroll
  for (int i=0;i<8;i++){
    int f = tid + i*256;
    int r = f >> 4;
    int k4 = (f & 15) << 2;
    float4 v = *(const float4*)&A[(size_t)(brow + r)*64 + k4];
    As[(k4+0)*132 + r] = v.x;
    As[(k4+1)*132 + r] = v.y;
    As[(k4+2)*132 + r] = v.z;
    As[(k4+3)*132 + r] = v.w;
  }
  #pragma unroll
  for (int i=0;i<8;i++){
    int f = tid + i*256;
    int k = f >> 5;
    int c4 = (f & 31) << 2;
    float4 v = *(const float4*)&B[(size_t)k*2048 + bcol + c4];
    *(float4*)&Bs[k*128 + c4] = v;
  }
  if (tid==0) sMin=0xFFFFFFFFu;
  __syncthreads();
  const int ty = tid >> 4, tx = tid & 15;
  const int m0 = ty*8, n0 = tx*8;
  float acc[8][8];
  #pragma unroll
  for (int i=0;i<8;i++)
    #pragma unroll
    for (int j=0;j<8;j++) acc[i][j]=0.0f;
  #pragma unroll 8
  for (int k=0;k<64;k++){
    float4 a0 = *(const float4*)(As + k*132 + m0);
    float4 a1 = *(const float4*)(As + k*132 + m0 + 4);
    float4 b0 = *(const float4*)(Bs + k*128 + n0);
    float4 b1 = *(const float4*)(Bs + k*128 + n0 + 4);
    float am[8] = {a0.x,a0.y,a0.z,a0.w,a1.x,a1.y,a1.z,a1.w};
    float bn[8] = {b0.x,b0.y,b0.z,b0.w,b1.x,b1.y,b1.z,b1.w};
    #pragma unroll
    for (int i=0;i<8;i++)
      #pragma unroll
      for (int j=0;j<8;j++)
        acc[i][j] = fmaf(am[i], bn[j], acc[i][j]);
  }
  __syncthreads();
  unsigned* sh = (unsigned*)As;
  for (int i=tid;i<4096;i+=256) sh[i]=0u;
  __syncthreads();
  unsigned lmin=0xFFFFFFFFu;
  #pragma unroll
  for (int i=0;i<8;i++){
    int r = brow + m0 + i;
    float4 o0 = make_float4(acc[i][0],acc[i][1],acc[i][2],acc[i][3]);
    float4 o1 = make_float4(acc[i][4],acc[i][5],acc[i][6],acc[i][7]);
    *(float4*)&C[(size_t)r*2048 + bcol + n0]     = o0;
    *(float4*)&C[(size_t)r*2048 + bcol + n0 + 4] = o1;
    #pragma unroll
    for (int j=0;j<8;j++){
      unsigned kk = f2key(acc[i][j]);
      atomicAdd(&sh[kk>>20], 1u);
      lmin = min(lmin, kk);
    }
  }
  atomicMin(&sMin, lmin);
  __syncthreads();
  for (int i=tid;i<4096;i+=256){ unsigned c=sh[i]; if(c) atomicAdd(&histO[i],c); }
  if (tid==0) atomicMin(minKeyO, sMin);
}

static void percentile_ranks(long long n, double pct, unsigned& k1, unsigned& k2, double& frac){
  double p = (double)(n - 1) * (pct / 100.0);
  double fi = floor(p);
  frac = p - fi;
  long long i0 = (long long)fi;
  k2 = (unsigned)(n - i0);   // rank (from top) of a[i0]
  k1 = k2 - 1u;              // rank of a[i0+1]
}

extern "C" void kernel_launch(void* const* d_in, const int* in_sizes, int n_in,
                              void* d_out, int out_size, void* d_ws, size_t ws_size,
                              hipStream_t stream) {
  const float* x = (const float*)d_in[0];
  const float* y = (const float*)d_in[1];
  float* out = (float*)d_out;
  char* ws = (char*)d_ws;

  const long long nX = (long long)in_sizes[0];       // 1048576
  const long long nY = (long long)in_sizes[1];       // 1048576
  const long long nO = (long long)out_size;          // 33554432
  const int nX4 = (int)(nX/4), nY4 = (int)(nY/4), nO4 = (int)(nO/4);

  float*    xq    = (float*)(ws);
  float*    yq    = (float*)(ws + (5ll<<20));
  float*    candx = (float*)(ws + (10ll<<20));
  float*    candy = (float*)(ws + (15ll<<20));
  float*    cando = (float*)(ws + (20ll<<20));
  unsigned* ctrl  = (unsigned*)(ws + (25ll<<20));
  unsigned *hx = ctrl, *hy = ctrl+4096, *ho = ctrl+8192;
  unsigned* minkey = ctrl + 12288;   // [3]: x,y,o
  unsigned* cnt    = ctrl + 12291;   // [3]
  unsigned* bix    = ctrl + 12294;   // [3] each
  unsigned* biy    = ctrl + 12297;
  unsigned* bio    = ctrl + 12300;
  float* stx = (float*)(ctrl + 12304);  // {mn,mx}
  float* sty = stx + 2;
  float* sto = stx + 4;

  unsigned k1x,k2x,k1y,k2y,k1o,k2o; double fx,fy,fo;
  percentile_ranks(nX, 99.99,   k1x, k2x, fx);
  percentile_ranks(nY, 98.0,    k1y, k2y, fy);
  percentile_ranks(nO, 99.9999, k1o, k2o, fo);

  init_kernel<<<48,256,0,stream>>>(ctrl);

  // ---- x & y stats + quant (merged dual-tensor pipeline) ----
  hist2_kernel<<<dim3(128,2),256,0,stream>>>((const float4*)x,(const float4*)y,nX4,nY4,hx,hy,minkey+0,minkey+1);
  findbin2_kernel<<<2,256,0,stream>>>(hx,hy,k1x,k2x,k1y,k2y,bix,biy);
  collect2_kernel<<<dim3(128,2),256,0,stream>>>((const float4*)x,(const float4*)y,nX4,nY4,bix,biy,candx,candy,cnt+0,cnt+1);
  select2_kernel<<<2,1024,0,stream>>>(candx,candy,cnt+0,cnt+1,bix,biy,minkey+0,minkey+1,
                                      k1x,k2x,k1y,k2y,fx,fy,stx,sty);
  quant2_kernel<<<dim3(256,2),256,0,stream>>>((const float4*)x,(const float4*)y,(float4*)xq,(float4*)yq,
                                              nX4,nY4,stx,sty,0.0f,0.05f);

  // ---- matmul (raw f32 out to d_out) + fused out-histogram/min ----
  matmul_kernel<<<dim3(16,16,8),256,0,stream>>>(xq, yq, out, ho, minkey+2);

  // ---- out stats + in-place quant (deterministic rounding; |err| <= 1 level) ----
  findbin2_kernel<<<1,256,0,stream>>>(ho,ho,k1o,k2o,k1o,k2o,bio,bio);
  collect2_kernel<<<dim3(2048,1),256,0,stream>>>((const float4*)out,(const float4*)out,nO4,nO4,bio,bio,cando,cando,cnt+2,cnt+2);
  select2_kernel<<<1,1024,0,stream>>>(cando,cando,cnt+2,cnt+2,bio,bio,minkey+2,minkey+2,
                                      k1o,k2o,k1o,k2o,fo,fo,sto,sto);
  quant2_kernel<<<dim3(2048,1),256,0,stream>>>((const float4*)out,(const float4*)out,(float4*)out,(float4*)out,
                                               nO4,nO4,sto,sto,0.0f,0.0f);
}

// Round 4
// 237.776 us; speedup vs baseline: 3.3509x; 1.3721x over previous
//
#include <hip/hip_runtime.h>
#include <math.h>

#define CAP  (1u<<20)
#define LCAP 12288
#define LBUF 4096

__device__ __forceinline__ unsigned f2key(float f){
  unsigned u = __float_as_uint(f);
  return (u & 0x80000000u) ? ~u : (u | 0x80000000u);
}
__device__ __forceinline__ float key2f(unsigned k){
  unsigned u = (k & 0x80000000u) ? (k & 0x7fffffffu) : ~k;
  return __uint_as_float(u);
}

// zero hists/counters, init min keys
__global__ void init_kernel(unsigned* ctrl){
  int tid = blockIdx.x*blockDim.x + threadIdx.x;
  int stride = gridDim.x*blockDim.x;
  for (int i=tid;i<12288;i+=stride) ctrl[i]=0u;
  if (tid<3){ ctrl[12288+tid]=0xFFFFFFFFu; ctrl[12291+tid]=0u; }
}

// 4096-bin histogram over key>>20, plus global min key; blockIdx.y picks tensor
__global__ __launch_bounds__(256) void hist2_kernel(
    const float4* __restrict__ dA, const float4* __restrict__ dB, int n4A, int n4B,
    unsigned* __restrict__ hA, unsigned* __restrict__ hB,
    unsigned* __restrict__ mkA, unsigned* __restrict__ mkB){
  const int z = blockIdx.y;
  const float4* __restrict__ data = z ? dB : dA;
  const int n4 = z ? n4B : n4A;
  unsigned* hist = z ? hB : hA;
  unsigned* minKey = z ? mkB : mkA;
  __shared__ unsigned sh[4096];
  __shared__ unsigned sMin;
  int tid = threadIdx.x;
  for (int i=tid;i<4096;i+=blockDim.x) sh[i]=0u;
  if (tid==0) sMin=0xFFFFFFFFu;
  __syncthreads();
  unsigned lmin=0xFFFFFFFFu;
  int idx = blockIdx.x*blockDim.x + tid;
  int stride = gridDim.x*blockDim.x;
  for (int i=idx;i<n4;i+=stride){
    float4 v = data[i];
    unsigned k0=f2key(v.x), k1=f2key(v.y), k2=f2key(v.z), k3=f2key(v.w);
    atomicAdd(&sh[k0>>20],1u); atomicAdd(&sh[k1>>20],1u);
    atomicAdd(&sh[k2>>20],1u); atomicAdd(&sh[k3>>20],1u);
    lmin = min(lmin, min(min(k0,k1),min(k2,k3)));
  }
  atomicMin(&sMin, lmin);
  __syncthreads();
  for (int i=tid;i<4096;i+=blockDim.x){ unsigned c=sh[i]; if(c) atomicAdd(&hist[i],c); }
  if (tid==0) atomicMin(minKey, sMin);
}

// parallel findbin: blockIdx.x picks tensor. 256 thr, 16 bins/thread, suffix scan.
// binInfo = {b_lo, b_hi, cntAbove(b_hi)}
__global__ __launch_bounds__(256) void findbin2_kernel(
    const unsigned* __restrict__ histA, const unsigned* __restrict__ histB,
    unsigned k1A, unsigned k2A, unsigned k1B, unsigned k2B,
    unsigned* __restrict__ biA, unsigned* __restrict__ biB){
  const int z = blockIdx.x;
  const unsigned* __restrict__ hist = z ? histB : histA;
  const unsigned k1 = z ? k1B : k1A;
  const unsigned k2 = z ? k2B : k2A;
  unsigned* bi = z ? biB : biA;
  __shared__ unsigned part[256];
  const int t = threadIdx.x;
  unsigned h[16];
  unsigned s = 0;
  #pragma unroll
  for (int i=0;i<16;i++){ h[i] = hist[t*16+i]; s += h[i]; }
  part[t] = s;
  __syncthreads();
  for (int off=1; off<256; off<<=1){
    unsigned add = (t+off<256) ? part[t+off] : 0u;
    __syncthreads();
    part[t] += add;
    __syncthreads();
  }
  unsigned cum = (t<255) ? part[t+1] : 0u;   // sum of bins above this chunk
  for (int i=15;i>=0;--i){
    unsigned hh = h[i];
    unsigned b = (unsigned)(t*16+i);
    if (cum < k1 && cum + hh >= k1){ bi[1] = b; bi[2] = cum; }
    if (cum < k2 && cum + hh >= k2){ bi[0] = b; }
    cum += hh;
  }
}

// collect elements whose bin in [b_lo, b_hi]; blockIdx.y picks tensor
// block-staged: LDS buffer + ONE global atomic per block (was ~6000 serialized
// same-address global atomics = 96.7us). Overflow falls back to direct path.
__global__ __launch_bounds__(256) void collect2_kernel(
    const float4* __restrict__ dA, const float4* __restrict__ dB, int n4A, int n4B,
    const unsigned* __restrict__ biA, const unsigned* __restrict__ biB,
    float* __restrict__ candA, float* __restrict__ candB,
    unsigned* __restrict__ cntA, unsigned* __restrict__ cntB){
  const int z = blockIdx.y;
  const float4* __restrict__ data = z ? dB : dA;
  const int n4 = z ? n4B : n4A;
  const unsigned* bi = z ? biB : biA;
  float* cand = z ? candB : candA;
  unsigned* cnt = z ? cntB : cntA;
  __shared__ float sc[LBUF];
  __shared__ unsigned scnt, sbase;
  if (threadIdx.x==0) scnt=0u;
  __syncthreads();
  unsigned blo = bi[0], bhi = bi[1];
  int idx = blockIdx.x*blockDim.x + threadIdx.x;
  int stride = gridDim.x*blockDim.x;
  for (int i=idx;i<n4;i+=stride){
    float4 v = data[i];
    float r[4] = {v.x,v.y,v.z,v.w};
    #pragma unroll
    for (int j=0;j<4;j++){
      unsigned b = f2key(r[j]) >> 20;
      if (b>=blo && b<=bhi){
        unsigned p = atomicAdd(&scnt,1u);
        if (p < LBUF) sc[p] = r[j];
        else { unsigned g = atomicAdd(cnt,1u); if (g<CAP) cand[g]=r[j]; }
      }
    }
  }
  __syncthreads();
  unsigned c = scnt; if (c > LBUF) c = LBUF;
  if (threadIdx.x==0 && c>0) sbase = atomicAdd(cnt, c);
  __syncthreads();
  for (unsigned i=threadIdx.x; i<c; i+=256){
    unsigned g = sbase + i;
    if (g < CAP) cand[g] = sc[i];
  }
}

// exact top-k1/k2 via 4-pass radix select over LDS-cached candidates; write {mn, mx}
__global__ __launch_bounds__(1024) void select2_kernel(
    const float* __restrict__ candA, const float* __restrict__ candB,
    const unsigned* __restrict__ cntA, const unsigned* __restrict__ cntB,
    const unsigned* __restrict__ biA, const unsigned* __restrict__ biB,
    const unsigned* __restrict__ mkA, const unsigned* __restrict__ mkB,
    unsigned k1A, unsigned k2A, unsigned k1B, unsigned k2B,
    double fracA, double fracB,
    float* __restrict__ stA, float* __restrict__ stB){
  const int z = blockIdx.x;
  const float* __restrict__ cand = z ? candB : candA;
  const unsigned* cnt = z ? cntB : cntA;
  const unsigned* bi  = z ? biB  : biA;
  const unsigned* mk  = z ? mkB  : mkA;
  const unsigned k1 = z ? k1B : k1A;
  const unsigned k2 = z ? k2B : k2A;
  const double frac = z ? fracB : fracA;
  float* stats = z ? stB : stA;

  __shared__ unsigned keys[LCAP];
  __shared__ unsigned hist[256];
  __shared__ unsigned scan[256];
  __shared__ unsigned sPrefix, sK;
  __shared__ unsigned sKey[2];
  const int t = threadIdx.x;
  unsigned m = *cnt; if (m > CAP) m = CAP;
  unsigned above = bi[2];
  for (unsigned i=t; i<m && i<LCAP; i+=1024) keys[i] = f2key(cand[i]);
  __syncthreads();

  for (int tg=0; tg<2; ++tg){
    unsigned k = ((tg==0) ? k1 : k2) - above;  // rank (from top) within candidate set
    unsigned prefix = 0u, pmask = 0u;
    for (int s=24; s>=0; s-=8){
      if (t<256) hist[t]=0u;
      __syncthreads();
      for (unsigned i=t;i<m;i+=1024){
        unsigned key = (i<LCAP) ? keys[i] : f2key(cand[i]);
        if ((key & pmask) == prefix) atomicAdd(&hist[(key>>s)&255u],1u);
      }
      __syncthreads();
      if (t<256) scan[t] = hist[t];
      __syncthreads();
      for (int off=1; off<256; off<<=1){
        unsigned add = (t<256 && t+off<256) ? scan[t+off] : 0u;
        __syncthreads();
        if (t<256) scan[t] += add;
        __syncthreads();
      }
      if (t<256){
        unsigned cumAbove = (t<255) ? scan[t+1] : 0u;  // strictly-above count
        if (cumAbove < k && cumAbove + hist[t] >= k){  // unique t satisfies this
          sPrefix = prefix | ((unsigned)t << s);
          sK = k - cumAbove;
        }
      }
      __syncthreads();
      prefix = sPrefix;
      pmask |= (255u << s);
      k = sK;
      __syncthreads();
    }
    if (t==0) sKey[tg] = prefix;
  }
  __syncthreads();
  if (t==0){
    float vhi = key2f(sKey[0]);   // (R-1)-th largest = a[i0+1]
    float vlo = key2f(sKey[1]);   // R-th largest     = a[i0]
    double mx = (double)vlo + frac * ((double)vhi - (double)vlo);
    float mxf = (float)mx;
    float mnraw = key2f(*mk);
    float mnf = (mnraw >= 0.0f) ? mnraw : -mxf;
    stats[0]=mnf; stats[1]=mxf;
  }
}

// fake-quant with optional lut shrinkage; STE value semantics; in/out may alias
// blockIdx.y picks tensor
__global__ __launch_bounds__(256) void quant2_kernel(
    const float4* __restrict__ inA, const float4* __restrict__ inB,
    float4* __restrict__ outA, float4* __restrict__ outB, int n4A, int n4B,
    const float* __restrict__ stA, const float* __restrict__ stB,
    float lutA, float lutB){
  const int z = blockIdx.y;
  const float4* __restrict__ in = z ? inB : inA;
  float4* outp = z ? outB : outA;
  const int n4 = z ? n4B : n4A;
  const float* stats = z ? stB : stA;
  const float lutMin = z ? lutB : lutA;
  float mn = stats[0], mx = stats[1];
  float diff = mx - mn;
  float denom = diff + 1e-8f;
  float lp = lutMin * mx;
  float ln = lutMin * fabsf(mn);
  int idx = blockIdx.x*blockDim.x + threadIdx.x;
  int stride = gridDim.x*blockDim.x;
  for (int i=idx;i<n4;i+=stride){
    float4 v = in[i];
    float r[4] = {v.x,v.y,v.z,v.w};
    #pragma unroll
    for (int j=0;j<4;j++){
      float x = r[j];
      float q = fminf(fmaxf(x, mn), mx);
      q = (q - mn) / denom * 255.0f;
      q = rintf(q);
      q = q / 255.0f * diff + mn;
      if (lutMin > 0.0f){
        float pos = fmaxf(q, 0.0f);
        float neg = q - pos;
        pos = (pos < lp) ? lp : pos;
        neg = (neg > -ln) ? -ln : neg;
        q = pos + neg;
      }
      r[j] = x + (q - x);
    }
    outp[i] = make_float4(r[0],r[1],r[2],r[3]);
  }
}

// batched f32 GEMM: A[b] 2048x64 row-major, B[b] 64x2048 row-major -> C[b] 2048x2048
// fused epilogue: histogram + min of C into histO/minKeyO
__global__ __launch_bounds__(256) void matmul_kernel(const float* __restrict__ A, const float* __restrict__ B,
                              float* __restrict__ C,
                              unsigned* __restrict__ histO, unsigned* __restrict__ minKeyO){
  __shared__ float As[64*132];   // [k][m], padded stride 132
  __shared__ float Bs[64*128];   // [k][n]
  __shared__ unsigned sMin;
  const int b = blockIdx.z;
  A += (size_t)b*2048*64;
  B += (size_t)b*64*2048;
  C += (size_t)b*2048*2048;
  const int brow = blockIdx.y*128, bcol = blockIdx.x*128;
  const int tid = threadIdx.x;
  #pragma unroll
  for (int i=0;i<8;i++){
    int f = tid + i*256;
    int r = f >> 4;
    int k4 = (f & 15) << 2;
    float4 v = *(const float4*)&A[(size_t)(brow + r)*64 + k4];
    As[(k4+0)*132 + r] = v.x;
    As[(k4+1)*132 + r] = v.y;
    As[(k4+2)*132 + r] = v.z;
    As[(k4+3)*132 + r] = v.w;
  }
  #pragma unroll
  for (int i=0;i<8;i++){
    int f = tid + i*256;
    int k = f >> 5;
    int c4 = (f & 31) << 2;
    float4 v = *(const float4*)&B[(size_t)k*2048 + bcol + c4];
    *(float4*)&Bs[k*128 + c4] = v;
  }
  if (tid==0) sMin=0xFFFFFFFFu;
  __syncthreads();
  const int ty = tid >> 4, tx = tid & 15;
  const int m0 = ty*8, n0 = tx*8;
  float acc[8][8];
  #pragma unroll
  for (int i=0;i<8;i++)
    #pragma unroll
    for (int j=0;j<8;j++) acc[i][j]=0.0f;
  #pragma unroll 8
  for (int k=0;k<64;k++){
    float4 a0 = *(const float4*)(As + k*132 + m0);
    float4 a1 = *(const float4*)(As + k*132 + m0 + 4);
    float4 b0 = *(const float4*)(Bs + k*128 + n0);
    float4 b1 = *(const float4*)(Bs + k*128 + n0 + 4);
    float am[8] = {a0.x,a0.y,a0.z,a0.w,a1.x,a1.y,a1.z,a1.w};
    float bn[8] = {b0.x,b0.y,b0.z,b0.w,b1.x,b1.y,b1.z,b1.w};
    #pragma unroll
    for (int i=0;i<8;i++)
      #pragma unroll
      for (int j=0;j<8;j++)
        acc[i][j] = fmaf(am[i], bn[j], acc[i][j]);
  }
  __syncthreads();
  unsigned* sh = (unsigned*)As;
  for (int i=tid;i<4096;i+=256) sh[i]=0u;
  __syncthreads();
  unsigned lmin=0xFFFFFFFFu;
  #pragma unroll
  for (int i=0;i<8;i++){
    int r = brow + m0 + i;
    float4 o0 = make_float4(acc[i][0],acc[i][1],acc[i][2],acc[i][3]);
    float4 o1 = make_float4(acc[i][4],acc[i][5],acc[i][6],acc[i][7]);
    *(float4*)&C[(size_t)r*2048 + bcol + n0]     = o0;
    *(float4*)&C[(size_t)r*2048 + bcol + n0 + 4] = o1;
    #pragma unroll
    for (int j=0;j<8;j++){
      unsigned kk = f2key(acc[i][j]);
      atomicAdd(&sh[kk>>20], 1u);
      lmin = min(lmin, kk);
    }
  }
  atomicMin(&sMin, lmin);
  __syncthreads();
  for (int i=tid;i<4096;i+=256){ unsigned c=sh[i]; if(c) atomicAdd(&histO[i],c); }
  if (tid==0) atomicMin(minKeyO, sMin);
}

static void percentile_ranks(long long n, double pct, unsigned& k1, unsigned& k2, double& frac){
  double p = (double)(n - 1) * (pct / 100.0);
  double fi = floor(p);
  frac = p - fi;
  long long i0 = (long long)fi;
  k2 = (unsigned)(n - i0);   // rank (from top) of a[i0]
  k1 = k2 - 1u;              // rank of a[i0+1]
}

extern "C" void kernel_launch(void* const* d_in, const int* in_sizes, int n_in,
                              void* d_out, int out_size, void* d_ws, size_t ws_size,
                              hipStream_t stream) {
  const float* x = (const float*)d_in[0];
  const float* y = (const float*)d_in[1];
  float* out = (float*)d_out;
  char* ws = (char*)d_ws;

  const long long nX = (long long)in_sizes[0];       // 1048576
  const long long nY = (long long)in_sizes[1];       // 1048576
  const long long nO = (long long)out_size;          // 33554432
  const int nX4 = (int)(nX/4), nY4 = (int)(nY/4), nO4 = (int)(nO/4);

  float*    xq    = (float*)(ws);
  float*    yq    = (float*)(ws + (5ll<<20));
  float*    candx = (float*)(ws + (10ll<<20));
  float*    candy = (float*)(ws + (15ll<<20));
  float*    cando = (float*)(ws + (20ll<<20));
  unsigned* ctrl  = (unsigned*)(ws + (25ll<<20));
  unsigned *hx = ctrl, *hy = ctrl+4096, *ho = ctrl+8192;
  unsigned* minkey = ctrl + 12288;   // [3]: x,y,o
  unsigned* cnt    = ctrl + 12291;   // [3]
  unsigned* bix    = ctrl + 12294;   // [3] each
  unsigned* biy    = ctrl + 12297;
  unsigned* bio    = ctrl + 12300;
  float* stx = (float*)(ctrl + 12304);  // {mn,mx}
  float* sty = stx + 2;
  float* sto = stx + 4;

  unsigned k1x,k2x,k1y,k2y,k1o,k2o; double fx,fy,fo;
  percentile_ranks(nX, 99.99,   k1x, k2x, fx);
  percentile_ranks(nY, 98.0,    k1y, k2y, fy);
  percentile_ranks(nO, 99.9999, k1o, k2o, fo);

  init_kernel<<<48,256,0,stream>>>(ctrl);

  // ---- x & y stats + quant (merged dual-tensor pipeline) ----
  hist2_kernel<<<dim3(128,2),256,0,stream>>>((const float4*)x,(const float4*)y,nX4,nY4,hx,hy,minkey+0,minkey+1);
  findbin2_kernel<<<2,256,0,stream>>>(hx,hy,k1x,k2x,k1y,k2y,bix,biy);
  collect2_kernel<<<dim3(128,2),256,0,stream>>>((const float4*)x,(const float4*)y,nX4,nY4,bix,biy,candx,candy,cnt+0,cnt+1);
  select2_kernel<<<2,1024,0,stream>>>(candx,candy,cnt+0,cnt+1,bix,biy,minkey+0,minkey+1,
                                      k1x,k2x,k1y,k2y,fx,fy,stx,sty);
  quant2_kernel<<<dim3(256,2),256,0,stream>>>((const float4*)x,(const float4*)y,(float4*)xq,(float4*)yq,
                                              nX4,nY4,stx,sty,0.0f,0.05f);

  // ---- matmul (raw f32 out to d_out) + fused out-histogram/min ----
  matmul_kernel<<<dim3(16,16,8),256,0,stream>>>(xq, yq, out, ho, minkey+2);

  // ---- out stats + in-place quant (deterministic rounding; |err| <= 1 level) ----
  findbin2_kernel<<<1,256,0,stream>>>(ho,ho,k1o,k2o,k1o,k2o,bio,bio);
  collect2_kernel<<<dim3(2048,1),256,0,stream>>>((const float4*)out,(const float4*)out,nO4,nO4,bio,bio,cando,cando,cnt+2,cnt+2);
  select2_kernel<<<1,1024,0,stream>>>(cando,cando,cnt+2,cnt+2,bio,bio,minkey+2,minkey+2,
                                      k1o,k2o,k1o,k2o,fo,fo,sto,sto);
  quant2_kernel<<<dim3(2048,1),256,0,stream>>>((const float4*)out,(const float4*)out,(float4*)out,(float4*)out,
                                               nO4,nO4,sto,sto,0.0f,0.0f);
}